// Round 4
// baseline (145.849 us; speedup 1.0000x reference)
//
#include <hip/hip_runtime.h>
#include <math.h>

// ALCOVE cell: B=256, D=64, H=2048, O=32
// RHO=2, TAU=1, BETA=6.5, GAMMA=0, PHI=2, LAM_A=0.001, LAM_W=0.003
//
// R4: K2 shfl-free — per-chunk partial dot products go to LDS (independent
// writes, 2-way bank alias = free), one barrier, then thread-per-h sums its
// own 8 partials (2x ds_read_b128) -> coeff.  No dependent cross-lane chains
// anywhere in the hot kernels.
//
//   K0: transpose coords -> ct[d][h]  (one-shot, 512 KB, L2-resident)
//   K1: thread-per-(b,h): S = sum_d att_d*(z_d-ct[d][h])^2, s=exp(-beta*d),
//       r = -beta*s/(2d); partial x_out -> ws.
//   K2: gx from partials, assoc update, g_s via LDS partials -> coeff,
//       partial g_att -> ws; writes out0 + out2
//   K3: finalize new_attention (out1)
//
// ws layout (floats):
//   ct[D*H]  s_all[B*H]  r_all[B*H]  px[B*8*O]  gatt_part[B*8*D]

#define BB 256
#define DD 64
#define HH 2048
#define OO 32
#define NSL 8
#define HS (HH / NSL)          // 256 h per slice/block
#define BETA 6.5f
#define PHI 2.0f
#define LAM_A 0.001f
#define LAM_W 0.003f
#define NT 256

__global__ __launch_bounds__(NT) void k0_transpose(
    const float* __restrict__ coords, float* __restrict__ ct)
{
    int idx = blockIdx.x * NT + threadIdx.x;   // 0 .. D*H-1, ct-linear
    int d = idx >> 11;                         // / HH
    int h = idx & (HH - 1);
    ct[idx] = coords[h * DD + d];
}

__global__ __launch_bounds__(NT) void k1_sim(
    const float* __restrict__ z,
    const float* __restrict__ att,
    const float* __restrict__ assoc,
    const float* __restrict__ ct,
    float* __restrict__ s_all,
    float* __restrict__ r_all,
    float* __restrict__ px)
{
    __shared__ float2 za[DD];      // (z_d, att_d)
    __shared__ float s_loc[HS];
    __shared__ float red[NT * 4];

    const int b  = blockIdx.x >> 3;
    const int sl = blockIdx.x & 7;
    const int base = sl * HS;
    const int t = threadIdx.x;
    const int h = base + t;        // thread-per-h

    if (t < DD)
        za[t] = make_float2(z[b * DD + t], att[b * DD + t]);
    __syncthreads();

    // ---- distance/similarity: coalesced ct column reads, no shuffles ----
    float S = 0.0f;
    const float* ctp = ct + h;
    #pragma unroll 8
    for (int d = 0; d < DD; ++d) {
        float2 p = za[d];                  // broadcast ds_read_b64
        float c = ctp[d * HH];             // coalesced across threads
        float diff = p.x - c;
        S = fmaf(p.y * diff, diff, S);
    }
    S = S < 0.0f ? 0.0f : S;
    float dd = sqrtf(S);
    float sh = expf(-BETA * dd);
    s_all[b * HH + h] = sh;
    r_all[b * HH + h] = (dd > 0.0f) ? (-BETA * sh / (2.0f * dd)) : 0.0f;
    s_loc[t] = sh;
    __syncthreads();

    // ---- partial x_out over this slice (float4 over o) ----
    const int o4 = t & 7;       // float4 column
    const int hl = t >> 3;      // 0..31
    const float4* assoc4 = (const float4*)(assoc + (size_t)b * HH * OO);

    float4 acc = make_float4(0.f, 0.f, 0.f, 0.f);
    #pragma unroll
    for (int chunk = 0; chunk < HS / 32; ++chunk) {
        int hloc = chunk * 32 + hl;
        float s2 = s_loc[hloc];
        float4 a = assoc4[(base + hloc) * (OO / 4) + o4];
        acc.x = fmaf(s2, a.x, acc.x);
        acc.y = fmaf(s2, a.y, acc.y);
        acc.z = fmaf(s2, a.z, acc.z);
        acc.w = fmaf(s2, a.w, acc.w);
    }
    ((float4*)red)[t] = acc;
    __syncthreads();

    if (t < OO) {
        const int b4 = t >> 2, comp = t & 3;
        float x = 0.0f;
        #pragma unroll 8
        for (int g = 0; g < 32; ++g)
            x += red[(g * 8 + b4) * 4 + comp];
        px[(b * NSL + sl) * OO + t] = x;
    }
}

__global__ __launch_bounds__(NT) void k2_upd(
    const float* __restrict__ z,
    const float* __restrict__ one_hot,
    const float* __restrict__ assoc,
    const float* __restrict__ coords,
    const float* __restrict__ s_all,
    const float* __restrict__ r_all,
    const float* __restrict__ px,
    float* __restrict__ gatt_part,
    float* __restrict__ out)
{
    __shared__ float gx_s[OO];
    __shared__ float s_loc[HS];
    __shared__ float r_loc[HS];
    __shared__ float coeff[HS];
    __shared__ float part_red[HS * 8];   // [hloc][o4] partial dots, 8 KB
    __shared__ float red[NT];

    const int b  = blockIdx.x >> 3;
    const int sl = blockIdx.x & 7;
    const int base = sl * HS;
    const int t = threadIdx.x;
    const int lane = t & 63;
    const int wave = t >> 6;

    if (t < OO) {
        float x = 0.0f;
        #pragma unroll
        for (int s2 = 0; s2 < NSL; ++s2)
            x += px[(b * NSL + s2) * OO + t];
        float oh = one_hot[b * OO + t];
        float tmin = fminf(-1.0f, x);
        float tmax = fmaxf(1.0f, x);
        float teacher = tmin - oh * tmin + oh * tmax;
        gx_s[t] = (2.0f / OO) * (x - teacher);
        if (sl == 0)
            out[b * OO + t] = PHI * x;                   // output 0
    }
    s_loc[t] = s_all[b * HH + base + t];
    r_loc[t] = r_all[b * HH + base + t];
    __syncthreads();

    // ---- assoc update + partial dots to LDS (no cross-lane ops) ----
    const int o4 = t & 7;
    const int hl = t >> 3;
    const float4 gxv = ((const float4*)gx_s)[o4];
    const float4* assoc4 = (const float4*)(assoc + (size_t)b * HH * OO);
    float4* out_assoc4 = (float4*)(out + BB * OO + BB * DD) + (size_t)b * HH * (OO / 4);

    #pragma unroll
    for (int chunk = 0; chunk < HS / 32; ++chunk) {
        int hloc = chunk * 32 + hl;
        float sh = s_loc[hloc];
        float4 a = assoc4[(base + hloc) * (OO / 4) + o4];
        float w = LAM_W * sh;
        float4 na;
        na.x = fmaf(-w, gxv.x, a.x);
        na.y = fmaf(-w, gxv.y, a.y);
        na.z = fmaf(-w, gxv.z, a.z);
        na.w = fmaf(-w, gxv.w, a.w);
        out_assoc4[(base + hloc) * (OO / 4) + o4] = na;  // output 2
        part_red[hloc * 8 + o4] =
            a.x * gxv.x + a.y * gxv.y + a.z * gxv.z + a.w * gxv.w;
    }
    __syncthreads();

    // ---- thread-per-h: g_s = sum of its 8 partials; coeff = r*g_s ----
    {
        const float4* pr = (const float4*)part_red + t * 2;
        float4 p0 = pr[0], p1 = pr[1];
        float g_s = (p0.x + p0.y) + (p0.z + p0.w)
                  + (p1.x + p1.y) + (p1.z + p1.w);
        coeff[t] = r_loc[t] * g_s;       // = -beta*s*g_s/(2d)
    }
    __syncthreads();

    // ---- partial g_att over this slice (lane == d) ----
    const float zd = z[b * DD + lane];
    float acc = 0.0f;
    #pragma unroll 4
    for (int i = 0; i < 64; ++i) {
        int hloc = wave * 64 + i;
        float cf = coeff[hloc];
        float c = coords[(base + hloc) * DD + lane];
        float diff = zd - c;
        acc = fmaf(cf * diff, diff, acc);
    }
    red[t] = acc;
    __syncthreads();

    if (t < DD) {
        float g = red[t] + red[64 + t] + red[128 + t] + red[192 + t];
        gatt_part[(b * NSL + sl) * DD + t] = g;
    }
}

__global__ __launch_bounds__(NT) void k3_att(
    const float* __restrict__ att,
    const float* __restrict__ gatt_part,
    float* __restrict__ out)
{
    int idx = blockIdx.x * NT + threadIdx.x;   // 0 .. B*D-1
    int b = idx >> 6;
    int d = idx & 63;
    float g = 0.0f;
    #pragma unroll
    for (int sl = 0; sl < NSL; ++sl)
        g += gatt_part[(b * NSL + sl) * DD + d];
    float na = att[b * DD + d] - LAM_A * g;
    out[BB * OO + idx] = na > 0.0f ? na : 0.0f;          // output 1
}

extern "C" void kernel_launch(void* const* d_in, const int* in_sizes, int n_in,
                              void* d_out, int out_size, void* d_ws, size_t ws_size,
                              hipStream_t stream) {
    const float* z       = (const float*)d_in[0];
    const float* one_hot = (const float*)d_in[1];
    const float* att     = (const float*)d_in[2];
    const float* assoc   = (const float*)d_in[3];
    const float* coords  = (const float*)d_in[4];
    float* out = (float*)d_out;

    float* ws = (float*)d_ws;
    float* ct        = ws;                            // D*H
    float* s_all     = ct + DD * HH;                  // B*H
    float* r_all     = s_all + BB * HH;               // B*H
    float* px        = r_all + BB * HH;               // B*8*O
    float* gatt_part = px + BB * NSL * OO;            // B*8*D

    k0_transpose<<<dim3((DD * HH) / NT), dim3(NT), 0, stream>>>(coords, ct);
    k1_sim<<<dim3(BB * NSL), dim3(NT), 0, stream>>>(z, att, assoc, ct,
                                                    s_all, r_all, px);
    k2_upd<<<dim3(BB * NSL), dim3(NT), 0, stream>>>(z, one_hot, assoc, coords,
                                                    s_all, r_all, px, gatt_part, out);
    k3_att<<<dim3((BB * DD) / NT), dim3(NT), 0, stream>>>(att, gatt_part, out);
}